// Round 11
// baseline (1063.238 us; speedup 1.0000x reference)
//
#include <hip/hip_runtime.h>

// RoIAlign: LDS-staged row-slabs + hoisted geometry table + compacted item lists.
//
// feature_map: (8, 256, 200, 200) f32; proposals: (8,256,4) i32;
// out: (2048, 256, 7, 7) f32.
//
// Evidence trail:
//  R2: ROI-per-block gather -> 916 MB HBM over-fetch, 371 us (L2 thrash).
//  R3: block-per-(b,c,half) LDS staging -> FETCH 161 MB, but 228 us at
//      VALUBusy 43%: geometry recomputed 512x per (roi,bin); half the scan
//      discarded by ownership test; only 2 blocks/CU (Occ 44%).
//  R4..R10 (this; never benched -- eight GPU-acquisition timeouts):
//      (a) geometry hoisted to 16B/item Rec table built once;
//      (b) precompute appends each item's u16 id to its (image,slab) list ->
//      gather touches only owned items (no divergence, half the table reads);
//      (c) 8 slabs x 26 staged rows = 20.8 KB static LDS -> 7 blocks/CU,
//      28 waves/CU, 7-way stage/gather overlap.

#define B_DIM 8
#define C_DIM 256
#define H_DIM 200
#define W_DIM 200
#define S_DIM 7
#define NBINS 49
#define NROI  256
#define R_TOT (B_DIM * NROI)        // 2048
#define IPI   (NROI * NBINS)        // 12544 items per image
#define NSLAB 8
#define SLAB_ROWS 25                // ya0 ownership granularity
#define STAGE_ROWS 26               // staged rows (tap pair needs +1 row)
#define GTHREADS 256

struct __align__(16) Rec {
    unsigned int coords;   // ya0 | xa0<<8 | ya1<<16 | xa1<<24  (all <= 199)
    unsigned int obase;    // (roi%256)*C_DIM*NBINS + bin
    float wy, wx;
};

// ---- ws layout ----
#define CNT_BYTES   256                                   // int cnt[64]
#define TAB_OFF     CNT_BYTES
#define TAB_BYTES   (B_DIM * IPI * (int)sizeof(Rec))      // 1,605,632
#define IDX_OFF     (TAB_OFF + TAB_BYTES)
#define IDX_BYTES   (B_DIM * NSLAB * IPI * 2)             // 1,605,632
#define WS_NEED     ((size_t)(IDX_OFF + IDX_BYTES))       // ~3.1 MB

__global__ __launch_bounds__(256) void precompute_kernel(
    const int4* __restrict__ props,
    Rec* __restrict__ tab,
    unsigned short* __restrict__ idxl,
    int* __restrict__ cnt)
{
    const int gid = blockIdx.x * 256 + threadIdx.x;
    if (gid >= R_TOT * NBINS) return;
    const int roi = gid / NBINS;            // global roi
    const int bin = gid - roi * NBINS;
    const int b   = roi >> 8;
    const int sy  = bin / S_DIM;
    const int sx  = bin - sy * S_DIM;

    const int4 p = props[roi];
    const int bx1 = min(max(p.x, 0), W_DIM - 1);
    const int by1 = min(max(p.y, 0), H_DIM - 1);
    const int bx2 = min(max(p.z, 0), W_DIM - 1);
    const int by2 = min(max(p.w, 0), H_DIM - 1);
    const int h = by2 - by1 + 1;
    const int w = bx2 - bx1 + 1;

    // Bit-match the reference: q = h/7.0f (division), then (sy+0.5)*q - 0.5
    const float qy = (float)h / (float)S_DIM;
    const float qx = (float)w / (float)S_DIM;
    const float src_y = fmaxf(((float)sy + 0.5f) * qy - 0.5f, 0.0f);
    const float src_x = fmaxf(((float)sx + 0.5f) * qx - 0.5f, 0.0f);
    const float y0f = floorf(src_y);
    const float x0f = floorf(src_x);
    const int y0 = (int)y0f;
    const int x0 = (int)x0f;
    const int y1 = min(y0 + 1, h - 1);
    const int x1 = min(x0 + 1, w - 1);
    const int ya0 = by1 + y0, ya1 = by1 + y1;
    const int xa0 = bx1 + x0, xa1 = bx1 + x1;

    Rec rec;
    rec.coords = (unsigned)ya0 | ((unsigned)xa0 << 8) |
                 ((unsigned)ya1 << 16) | ((unsigned)xa1 << 24);
    rec.obase  = (unsigned)((roi & (NROI - 1)) * (C_DIM * NBINS) + bin);
    rec.wy = src_y - y0f;
    rec.wx = src_x - x0f;

    const int item = gid - b * IPI;         // within-image item id (< 12544)
    tab[gid] = rec;

    const int slab = ya0 / SLAB_ROWS;       // 0..7 (ya0 <= 199)
    const int pos  = atomicAdd(&cnt[b * NSLAB + slab], 1);
    idxl[(b * NSLAB + slab) * IPI + pos] = (unsigned short)item;
}

__global__ __launch_bounds__(GTHREADS) void roialign_gather(
    const float* __restrict__ fm,
    const Rec*   __restrict__ tab,
    const unsigned short* __restrict__ idxl,
    const int*   __restrict__ cnt,
    float*       __restrict__ out)
{
    __shared__ float sPlane[STAGE_ROWS * W_DIM];   // 20,800 B -> 7 blocks/CU

    const int bid  = blockIdx.x;
    const int slab = bid & 7;
    const int c    = (bid >> 3) & (C_DIM - 1);
    const int b    = bid >> 11;
    const int r0   = slab * SLAB_ROWS;
    const int nrows = (slab == NSLAB - 1) ? SLAB_ROWS : STAGE_ROWS;  // last slab: rows 175..199
    const int nch   = nrows * (W_DIM / 4);

    const float4* __restrict__ src =
        (const float4*)(fm + ((size_t)(b * C_DIM + c)) * (H_DIM * W_DIM) + (size_t)r0 * W_DIM);
    float4* dst4 = (float4*)sPlane;
    for (int k = threadIdx.x; k < nch; k += GTHREADS)
        dst4[k] = src[k];

    const int n = cnt[b * NSLAB + slab];    // uniform scalar load
    __syncthreads();

    const unsigned short* __restrict__ il = idxl + (b * NSLAB + slab) * IPI;
    const Rec* __restrict__ tb = tab + b * IPI;
    float* __restrict__ outb =
        out + (size_t)b * ((size_t)NROI * C_DIM * NBINS) + (size_t)c * NBINS;

    for (int t = threadIdx.x; t < n; t += GTHREADS) {
        const int item = il[t];
        const uint4 rv = *(const uint4*)(tb + item);
        const int ya0 = rv.x & 255;
        const int xa0 = (rv.x >> 8) & 255;
        const int ya1 = (rv.x >> 16) & 255;
        const int xa1 = rv.x >> 24;
        const float wy = __uint_as_float(rv.z);
        const float wx = __uint_as_float(rv.w);
        const int ry0 = ya0 - r0;
        const int ry1 = ya1 - r0;

        const float v00 = sPlane[ry0 * W_DIM + xa0];
        const float v01 = sPlane[ry0 * W_DIM + xa1];
        const float v10 = sPlane[ry1 * W_DIM + xa0];
        const float v11 = sPlane[ry1 * W_DIM + xa1];

        const float top = v00 + (v01 - v00) * wx;
        const float bot = v10 + (v11 - v10) * wx;
        outb[rv.y] = top + (bot - top) * wy;
    }
}

// ---------- fallback (round-3 kernel, no ws dependency; proven correct) ----------
#define ROWS_HALF0 101
#define FB_LDS (ROWS_HALF0 * W_DIM * 4)
#define FB_THREADS 512

__global__ __launch_bounds__(FB_THREADS) void roialign_fallback(
    const float* __restrict__ fm, const int* __restrict__ props, float* __restrict__ out)
{
    extern __shared__ float sP[];
    const int bid  = blockIdx.x;
    const int half = bid & 1;
    const int c    = (bid >> 1) & (C_DIM - 1);
    const int b    = bid >> 9;
    const int r0   = half ? 100 : 0;
    const int nch  = (half ? (H_DIM - 100) : ROWS_HALF0) * (W_DIM / 4);

    const float4* __restrict__ src =
        (const float4*)(fm + ((size_t)(b * C_DIM + c)) * (H_DIM * W_DIM) + (size_t)r0 * W_DIM);
    float4* dst4 = (float4*)sP;
    for (int k = threadIdx.x; k < nch; k += FB_THREADS) dst4[k] = src[k];
    __syncthreads();

    const int4* __restrict__ pbase = (const int4*)props + (size_t)b * NROI;
    for (int item = threadIdx.x; item < NROI * NBINS; item += FB_THREADS) {
        const int roi = item / NBINS;
        const int bin = item - roi * NBINS;
        const int sy = bin / S_DIM, sx = bin - sy * S_DIM;
        const int4 p = pbase[roi];
        const int bx1 = min(max(p.x, 0), W_DIM - 1);
        const int by1 = min(max(p.y, 0), H_DIM - 1);
        const int bx2 = min(max(p.z, 0), W_DIM - 1);
        const int by2 = min(max(p.w, 0), H_DIM - 1);
        const int h = by2 - by1 + 1, w = bx2 - bx1 + 1;
        const float src_y = fmaxf(((float)sy + 0.5f) * ((float)h / (float)S_DIM) - 0.5f, 0.0f);
        const float y0f = floorf(src_y);
        const float wy = src_y - y0f;
        const int y0 = (int)y0f;
        const int y1 = min(y0 + 1, h - 1);
        const int ya0 = by1 + y0, ya1 = by1 + y1;
        const bool mine = half ? (ya0 >= 100) : (ya0 <= 99);
        if (!mine) continue;
        const float src_x = fmaxf(((float)sx + 0.5f) * ((float)w / (float)S_DIM) - 0.5f, 0.0f);
        const float x0f = floorf(src_x);
        const float wx = src_x - x0f;
        const int x0 = (int)x0f;
        const int x1 = min(x0 + 1, w - 1);
        const int xa0 = bx1 + x0, xa1 = bx1 + x1;
        const float v00 = sP[(ya0 - r0) * W_DIM + xa0];
        const float v01 = sP[(ya0 - r0) * W_DIM + xa1];
        const float v10 = sP[(ya1 - r0) * W_DIM + xa0];
        const float v11 = sP[(ya1 - r0) * W_DIM + xa1];
        const float top = v00 + (v01 - v00) * wx;
        const float bot = v10 + (v11 - v10) * wx;
        out[(((size_t)(b * NROI + roi)) * C_DIM + c) * NBINS + bin] = top + (bot - top) * wy;
    }
}

extern "C" void kernel_launch(void* const* d_in, const int* in_sizes, int n_in,
                              void* d_out, int out_size, void* d_ws, size_t ws_size,
                              hipStream_t stream)
{
    const float* fm    = (const float*)d_in[0];
    const int*   props = (const int*)d_in[1];
    float*       out   = (float*)d_out;

    if (ws_size >= WS_NEED) {
        int* cnt = (int*)d_ws;
        Rec* tab = (Rec*)((char*)d_ws + TAB_OFF);
        unsigned short* idxl = (unsigned short*)((char*)d_ws + IDX_OFF);

        hipMemsetAsync(cnt, 0, CNT_BYTES, stream);
        precompute_kernel<<<(R_TOT * NBINS) / 256, 256, 0, stream>>>(
            (const int4*)props, tab, idxl, cnt);
        roialign_gather<<<B_DIM * C_DIM * NSLAB, GTHREADS, 0, stream>>>(
            fm, tab, idxl, cnt, out);
    } else {
        hipFuncSetAttribute((const void*)roialign_fallback,
                            hipFuncAttributeMaxDynamicSharedMemorySize, FB_LDS);
        roialign_fallback<<<B_DIM * C_DIM * 2, FB_THREADS, FB_LDS, stream>>>(fm, props, out);
    }
}